// Round 8
// baseline (87.301 us; speedup 1.0000x reference)
//
#include <hip/hip_runtime.h>
#include <hip/hip_bf16.h>

#define B_ 32
#define N_ 1024
#define F_ 128
#define ALPHA_ 0.2f
#define PSTR 72   // padded LDS row stride in bf16 elems (144 B = 9 x 16B slots)

typedef __attribute__((ext_vector_type(8))) short short8_t;
typedef __attribute__((ext_vector_type(4))) short short4_t;
typedef __attribute__((ext_vector_type(4))) float f32x4;

static __device__ __forceinline__ unsigned short bf16b(float f) {
    return __bfloat16_as_ushort(__float2bfloat16(f));
}

#define WAIT_VM4()  asm volatile("s_waitcnt vmcnt(4)" ::: "memory")
#define WAIT_VM2()  asm volatile("s_waitcnt vmcnt(2)" ::: "memory")
#define WAIT_VM0()  asm volatile("s_waitcnt vmcnt(0)" ::: "memory")
#define WAIT_LGKM() asm volatile("s_waitcnt lgkmcnt(0)" ::: "memory")
#define SCHEDB()    __builtin_amdgcn_sched_barrier(0)
#define BAR()       __builtin_amdgcn_s_barrier()

// ---------------------------------------------------------------------------
// Kernel A: hT = bf16(feat @ W^T) transposed; s = h@a_src; t = h@a_dst.
// (fused transpose epilogue — verified mapping, R7)
// ---------------------------------------------------------------------------
__global__ __launch_bounds__(256) void hst_kernel(
    const float* __restrict__ feat, const float* __restrict__ W,
    const float* __restrict__ a, unsigned short* __restrict__ hT,
    float* __restrict__ s_out, float* __restrict__ t_out)
{
    __shared__ unsigned short Wt[128 * 128];
    __shared__ float fl[64 * 128];
    const int tid = threadIdx.x;
    const long row0 = (long)blockIdx.x * 64;
    const int b  = (int)(row0 >> 10);
    const int jb = (int)(row0 & 1023);

    for (int i = tid; i < 128 * 128; i += 256) {
        int d = i >> 7, k = i & 127;
        Wt[k * 128 + d] = bf16b(W[i]);
    }
    for (int i = tid; i < 64 * 128; i += 256) {
        int r = i >> 7, k = i & 127;
        fl[r * 128 + ((k + 8 * (r >> 2)) & 127)] =
            __builtin_nontemporal_load(&feat[(row0 + r) * 128 + k]);
    }
    __syncthreads();

    const int oct = tid & 15;
    const int rg  = tid >> 4;
    const int d0  = oct * 8;
    const int r0  = rg * 4;

    float acc[4][8];
    #pragma unroll
    for (int q = 0; q < 4; ++q)
        #pragma unroll
        for (int c = 0; c < 8; ++c) acc[q][c] = 0.f;

    for (int kc = 0; kc < 128; kc += 4) {
        float wv[4][8];
        #pragma unroll
        for (int kk = 0; kk < 4; ++kk) {
            short8_t wr = *reinterpret_cast<const short8_t*>(&Wt[(kc + kk) * 128 + d0]);
            #pragma unroll
            for (int c = 0; c < 8; ++c) {
                union { unsigned u; float f; } cv;
                cv.u = ((unsigned)(unsigned short)wr[c]) << 16;
                wv[kk][c] = cv.f;
            }
        }
        #pragma unroll
        for (int q = 0; q < 4; ++q) {
            int r = r0 + q;
            int koff = (kc + 8 * (r >> 2)) & 127;
            float4 fv = *reinterpret_cast<const float4*>(&fl[r * 128 + koff]);
            float fq[4] = {fv.x, fv.y, fv.z, fv.w};
            #pragma unroll
            for (int kk = 0; kk < 4; ++kk)
                #pragma unroll
                for (int c = 0; c < 8; ++c)
                    acc[q][c] = fmaf(fq[kk], wv[kk][c], acc[q][c]);
        }
    }

    // transposed bf16 write: hT[(b*128 + d)*1024 + jb + r0 + q]
    #pragma unroll
    for (int c = 0; c < 8; ++c) {
        short4_t hp;
        #pragma unroll
        for (int q = 0; q < 4; ++q) hp[q] = (short)bf16b(acc[q][c]);
        *reinterpret_cast<short4_t*>(
            &hT[((size_t)b * 128 + d0 + c) * 1024 + jb + r0]) = hp;
    }

    float asrc[8], adst[8];
    #pragma unroll
    for (int c = 0; c < 8; ++c) { asrc[c] = a[d0 + c]; adst[c] = a[128 + d0 + c]; }

    #pragma unroll
    for (int q = 0; q < 4; ++q) {
        long row = row0 + r0 + q;
        float sv = 0.f, tv = 0.f;
        #pragma unroll
        for (int c = 0; c < 8; ++c) {
            sv = fmaf(acc[q][c], asrc[c], sv);
            tv = fmaf(acc[q][c], adst[c], tv);
        }
        #pragma unroll
        for (int off = 1; off < 16; off <<= 1) {
            sv += __shfl_xor(sv, off);
            tv += __shfl_xor(tv, off);
        }
        if (oct == 0) { s_out[row] = sv; t_out[row] = tv; }
    }
}

// ---------------------------------------------------------------------------
// Kernel B v8: fused MFMA attention; NT adj DMA, TRUE depth-2 pipeline with
// DUAL h_reg buffers (fixes R7's register-clobber: LOAD_H(k+1) must not
// overwrite h(k) before it is staged). Counted vmcnt never drains mid-loop.
// Queue invariant at step g: [adj(k+1)(2), h(k+1)(2), adj(k+2)(2)] -> VM4
// retires exactly adj(k+1).
// ---------------------------------------------------------------------------
__global__ __launch_bounds__(512, 4) void attn4_kernel(
    const float* __restrict__ adj, const unsigned short* __restrict__ hT,
    const float* __restrict__ s_in, const float* __restrict__ t_in,
    float* __restrict__ out)
{
    __shared__ float adjb[3][64 * 64];            // 48 KB, DMA triple-buffer
    __shared__ unsigned short ht[128 * PSTR];     // 18 KB
    __shared__ unsigned short pt[64 * PSTR];      //  9 KB
    __shared__ float tl[N_];                      //  4 KB
    __shared__ float sl[64], rsl[64];

    const int tid  = threadIdx.x;
    const int lane = tid & 63;
    const int w    = tid >> 6;

    // XCD-chunked swizzle: XCD x gets contiguous blk range [64x, 64x+64)
    const int blk = (blockIdx.x & 7) * 64 + (blockIdx.x >> 3);
    const int b   = blk >> 4;
    const int i0  = (blk & 15) * 64;

    tl[tid]       = t_in[b * N_ + tid];
    tl[tid + 512] = t_in[b * N_ + tid + 512];
    if (tid < 64) sl[tid] = s_in[b * N_ + i0 + tid];

    // adj DMA addressing: issue q of wave w covers rows w*8+q*4+(lane>>4),
    // cols (lane&15)*4 (16B per lane)
    const int sr = w * 8 + (lane >> 4);
    const int sc = (lane & 15) * 4;
    const float* gsrc = adj + (size_t)(b * N_ + i0) * N_;

#define STAGE_ADJ(K, BUF) do {                                                 \
    __builtin_amdgcn_global_load_lds(                                          \
        (const __attribute__((address_space(1))) void*)                        \
            (gsrc + (size_t)sr * N_ + (K) * 64 + sc),                          \
        (__attribute__((address_space(3))) void*)&adjb[BUF][(w * 2 + 0) * 256],\
        16, 0, 2 /* nt */);                                                    \
    __builtin_amdgcn_global_load_lds(                                          \
        (const __attribute__((address_space(1))) void*)                        \
            (gsrc + (size_t)(sr + 4) * N_ + (K) * 64 + sc),                    \
        (__attribute__((address_space(3))) void*)&adjb[BUF][(w * 2 + 1) * 256],\
        16, 0, 2 /* nt */);                                                    \
} while (0)

    const unsigned short* hTb = hT + (size_t)b * F_ * N_;
    short8_t h_reg[2][2];     // DUAL buffer: [K&1][chunk] — static after unroll
#define LOAD_H(K) do {                                                         \
    _Pragma("unroll")                                                          \
    for (int c = 0; c < 2; ++c) {                                              \
        int ch = tid + c * 512;                                                \
        h_reg[(K) & 1][c] = *reinterpret_cast<const short8_t*>(                \
            hTb + (size_t)(ch >> 3) * N_ + ((K) * 64 + (ch & 7) * 8));         \
    }                                                                          \
} while (0)

    const int gi = tid >> 3;
    const int gj = (tid & 7) * 8;
    const int m0 = (w >> 2) * 32;
    const int n0 = (w & 3) * 32;
    const int lm = tid & 15;
    const int kg = (tid & 63) >> 4;

    f32x4 acc[2][2];
    #pragma unroll
    for (int nf = 0; nf < 2; ++nf)
        #pragma unroll
        for (int mf = 0; mf < 2; ++mf) acc[nf][mf] = (f32x4){0.f, 0.f, 0.f, 0.f};
    float rs = 0.f;

    // ---- prologue: queue = [adj0(2), h0(2), adj1(2)]; VM4 retires adj0.
    STAGE_ADJ(0, 0);
    LOAD_H(0);
    STAGE_ADJ(1, 1);
    WAIT_VM4();
    WAIT_LGKM();         // tl/sl visible
    SCHEDB();
    BAR();
    const float s_i = sl[gi];

    #pragma unroll
    for (int k = 0; k < 16; ++k) {
        // a. issue h(k+1) into the OTHER register buffer (older than adj(k+2))
        if (k + 1 < 16) LOAD_H(k + 1);
        // b. issue adj(k+2) DMA (two iterations of flight time)
        if (k + 2 < 16) STAGE_ADJ(k + 2, (k + 2) % 3);
        // c. stage ht from h_reg[k&1] (compiler retires h(k) only:
        //    adj(k+1), h(k+1), adj(k+2) stay in flight)
        #pragma unroll
        for (int c = 0; c < 2; ++c) {
            int ch = tid + c * 512;
            *reinterpret_cast<short8_t*>(&ht[(ch >> 3) * PSTR + (ch & 7) * 8]) =
                h_reg[k & 1][c];
        }
        // d. P-gen from adjb[k%3] (arrival proven at iter k-1 step g)
        {
            const float* ab = &adjb[k % 3][gi * 64 + gj];
            float4 a0 = *reinterpret_cast<const float4*>(ab);
            float4 a1 = *reinterpret_cast<const float4*>(ab + 4);
            float4 t0 = *reinterpret_cast<const float4*>(&tl[k * 64 + gj]);
            float4 t1 = *reinterpret_cast<const float4*>(&tl[k * 64 + gj + 4]);
            short4_t pk0, pk1;
            #pragma unroll
            for (int e = 0; e < 4; ++e) {
                float sc0 = s_i + (&t0.x)[e];
                sc0 = fmaxf(sc0, ALPHA_ * sc0);
                float p = __expf(sc0) * (&a0.x)[e];   // adj is exactly 0.0/1.0
                rs += p;
                pk0[e] = (short)bf16b(p);
            }
            #pragma unroll
            for (int e = 0; e < 4; ++e) {
                float sc1 = s_i + (&t1.x)[e];
                sc1 = fmaxf(sc1, ALPHA_ * sc1);
                float p = __expf(sc1) * (&a1.x)[e];
                rs += p;
                pk1[e] = (short)bf16b(p);
            }
            *reinterpret_cast<short4_t*>(&pt[gi * PSTR + gj])     = pk0;
            *reinterpret_cast<short4_t*>(&pt[gi * PSTR + gj + 4]) = pk1;
        }
        // e. ht/pt visible to all waves
        WAIT_LGKM();
        SCHEDB();
        BAR();
        // f. MFMA
        #pragma unroll
        for (int ks = 0; ks < 2; ++ks) {
            short8_t b0 = *reinterpret_cast<const short8_t*>(
                &ht[(n0 + lm) * PSTR + ks * 32 + kg * 8]);
            short8_t b1 = *reinterpret_cast<const short8_t*>(
                &ht[(n0 + 16 + lm) * PSTR + ks * 32 + kg * 8]);
            short8_t a0f = *reinterpret_cast<const short8_t*>(
                &pt[(m0 + lm) * PSTR + ks * 32 + kg * 8]);
            short8_t a1f = *reinterpret_cast<const short8_t*>(
                &pt[(m0 + 16 + lm) * PSTR + ks * 32 + kg * 8]);
            acc[0][0] = __builtin_amdgcn_mfma_f32_16x16x32_bf16(a0f, b0, acc[0][0], 0, 0, 0);
            acc[1][0] = __builtin_amdgcn_mfma_f32_16x16x32_bf16(a0f, b1, acc[1][0], 0, 0, 0);
            acc[0][1] = __builtin_amdgcn_mfma_f32_16x16x32_bf16(a1f, b0, acc[0][1], 0, 0, 0);
            acc[1][1] = __builtin_amdgcn_mfma_f32_16x16x32_bf16(a1f, b1, acc[1][1], 0, 0, 0);
        }
        // g. prove adj(k+1) arrived; keep h(k+1)+adj(k+2) in flight
        if (k + 2 < 16)      { WAIT_VM4(); }
        else if (k + 1 < 16) { WAIT_VM2(); }
        else                 { WAIT_VM0(); }
        SCHEDB();
        BAR();
    }

    // rowsum over the 8 threads sharing gi
    rs += __shfl_xor(rs, 1);
    rs += __shfl_xor(rs, 2);
    rs += __shfl_xor(rs, 4);
    if ((tid & 7) == 0) rsl[gi] = 1.0f / rs;
    __syncthreads();

    const int rbase = m0 + ((tid & 63) >> 4) * 4;
    float* ob = out + ((size_t)(b * N_ + i0)) * F_;
    #pragma unroll
    for (int mf = 0; mf < 2; ++mf) {
        f32x4 inv = *reinterpret_cast<const f32x4*>(&rsl[rbase + mf * 16]);
        #pragma unroll
        for (int r = 0; r < 4; ++r) {
            int row = rbase + mf * 16 + r;
            #pragma unroll
            for (int nf = 0; nf < 2; ++nf)
                __builtin_nontemporal_store(
                    acc[nf][mf][r] * inv[r],
                    &ob[(size_t)row * F_ + n0 + nf * 16 + lm]);
        }
    }
#undef STAGE_ADJ
#undef LOAD_H
}

// ---------------------------------------------------------------------------
extern "C" void kernel_launch(void* const* d_in, const int* in_sizes, int n_in,
                              void* d_out, int out_size, void* d_ws, size_t ws_size,
                              hipStream_t stream)
{
    const float* adj  = (const float*)d_in[0];   // (32,1024,1024)
    const float* feat = (const float*)d_in[1];   // (32,1024,128)
    const float* W    = (const float*)d_in[2];   // (128,128)
    const float* a    = (const float*)d_in[3];   // (256,1)
    float* out = (float*)d_out;                  // (32,1024,128) fp32

    unsigned short* hT = (unsigned short*)d_ws;                          // 8 MB
    float* s = (float*)((char*)d_ws + (size_t)B_ * F_ * N_ * 2);         // 128 KB
    float* t = s + (size_t)B_ * N_;                                      // 128 KB

    hst_kernel<<<(B_ * N_) / 64, 256, 0, stream>>>(feat, W, a, hT, s, t);
    attn4_kernel<<<B_ * 16, 512, 0, stream>>>(adj, hT, s, t, out);
}

// Round 9
// 62.271 us; speedup vs baseline: 1.4020x; 1.4020x over previous
//
#include <hip/hip_runtime.h>
#include <hip/hip_bf16.h>

#define B_ 32
#define N_ 1024
#define F_ 128
#define ALPHA_ 0.2f
#define PSTR 72   // padded LDS row stride in bf16 elems (144 B = 9 x 16B slots)

typedef __attribute__((ext_vector_type(8))) short short8_t;
typedef __attribute__((ext_vector_type(4))) short short4_t;
typedef __attribute__((ext_vector_type(4))) float f32x4;

static __device__ __forceinline__ unsigned short bf16b(float f) {
    return __bfloat16_as_ushort(__float2bfloat16(f));
}

#define WAIT_LGKM() asm volatile("s_waitcnt lgkmcnt(0)" ::: "memory")
#define SCHEDB()    __builtin_amdgcn_sched_barrier(0)
#define BAR()       __builtin_amdgcn_s_barrier()

// ---------------------------------------------------------------------------
// Kernel A v2: hT = bf16(feat @ W^T) via IN-LDS transpose (coalesced hT
// writes); s = h@a_src; t = h@a_dst. tr_kernel eliminated.
// ---------------------------------------------------------------------------
__global__ __launch_bounds__(256) void hst_kernel(
    const float* __restrict__ feat, const float* __restrict__ W,
    const float* __restrict__ a, unsigned short* __restrict__ hT,
    float* __restrict__ s_out, float* __restrict__ t_out)
{
    __shared__ unsigned short Wt[128 * 128];
    __shared__ float fl[64 * 128];
    const int tid = threadIdx.x;
    const long row0 = (long)blockIdx.x * 64;
    const int b  = (int)(row0 >> 10);
    const int jb = (int)(row0 & 1023);

    for (int i = tid; i < 128 * 128; i += 256) {
        int d = i >> 7, k = i & 127;
        Wt[k * 128 + d] = bf16b(W[i]);
    }
    for (int i = tid; i < 64 * 128; i += 256) {
        int r = i >> 7, k = i & 127;
        fl[r * 128 + ((k + 8 * (r >> 2)) & 127)] = feat[(row0 + r) * 128 + k];
    }
    __syncthreads();

    const int oct = tid & 15;
    const int rg  = tid >> 4;
    const int d0  = oct * 8;
    const int r0  = rg * 4;

    float acc[4][8];
    #pragma unroll
    for (int q = 0; q < 4; ++q)
        #pragma unroll
        for (int c = 0; c < 8; ++c) acc[q][c] = 0.f;

    for (int kc = 0; kc < 128; kc += 4) {
        float wv[4][8];
        #pragma unroll
        for (int kk = 0; kk < 4; ++kk) {
            short8_t wr = *reinterpret_cast<const short8_t*>(&Wt[(kc + kk) * 128 + d0]);
            #pragma unroll
            for (int c = 0; c < 8; ++c) {
                union { unsigned u; float f; } cv;
                cv.u = ((unsigned)(unsigned short)wr[c]) << 16;
                wv[kk][c] = cv.f;
            }
        }
        #pragma unroll
        for (int q = 0; q < 4; ++q) {
            int r = r0 + q;
            int koff = (kc + 8 * (r >> 2)) & 127;
            float4 fv = *reinterpret_cast<const float4*>(&fl[r * 128 + koff]);
            float fq[4] = {fv.x, fv.y, fv.z, fv.w};
            #pragma unroll
            for (int kk = 0; kk < 4; ++kk)
                #pragma unroll
                for (int c = 0; c < 8; ++c)
                    acc[q][c] = fmaf(fq[kk], wv[kk][c], acc[q][c]);
        }
    }

    // s/t reductions (independent of the transpose staging below)
    float asrc[8], adst[8];
    #pragma unroll
    for (int c = 0; c < 8; ++c) { asrc[c] = a[d0 + c]; adst[c] = a[128 + d0 + c]; }
    #pragma unroll
    for (int q = 0; q < 4; ++q) {
        long row = row0 + r0 + q;
        float sv = 0.f, tv = 0.f;
        #pragma unroll
        for (int c = 0; c < 8; ++c) {
            sv = fmaf(acc[q][c], asrc[c], sv);
            tv = fmaf(acc[q][c], adst[c], tv);
        }
        #pragma unroll
        for (int off = 1; off < 16; off <<= 1) {
            sv += __shfl_xor(sv, off);
            tv += __shfl_xor(tv, off);
        }
        if (oct == 0) { s_out[row] = sv; t_out[row] = tv; }
    }

    // ---- in-LDS transpose: fl reused as [j][swizzled d] fp32 ----
    __syncthreads();   // everyone done READING fl in the GEMM loop
    #pragma unroll
    for (int q = 0; q < 4; ++q) {
        int r = r0 + q;
        // phys col = (d + 4*(r>>2)) & 127 ; r>>2 == rg for q in [0,4)
        int base0 = (d0 + 4 * rg) & 127;       // cols d0..d0+3
        int base1 = (d0 + 4 + 4 * rg) & 127;   // cols d0+4..d0+7
        *reinterpret_cast<float4*>(&fl[r * 128 + base0]) =
            make_float4(acc[q][0], acc[q][1], acc[q][2], acc[q][3]);
        *reinterpret_cast<float4*>(&fl[r * 128 + base1]) =
            make_float4(acc[q][4], acc[q][5], acc[q][6], acc[q][7]);
    }
    __syncthreads();

    // coalesced bf16 write: thread -> d = tid>>1, half = tid&1 (32 j's)
    {
        const int d    = tid >> 1;
        const int half = tid & 1;
        unsigned short* dst = hT + ((size_t)b * F_ + d) * N_ + jb + half * 32;
        #pragma unroll
        for (int qq = 0; qq < 4; ++qq) {
            short8_t pk;
            #pragma unroll
            for (int e = 0; e < 8; ++e) {
                int j = half * 32 + qq * 8 + e;
                pk[e] = (short)bf16b(fl[j * 128 + ((d + 4 * (j >> 2)) & 127)]);
            }
            *reinterpret_cast<short8_t*>(dst + qq * 8) = pk;
        }
    }
}

// ---------------------------------------------------------------------------
// Kernel B v9: fused MFMA attention, REGISTER-staged adj (no adjb LDS, no
// global_load_lds). Dual-buffered regs prefetch tile k+1 before staging k;
// raw lgkm-only barriers keep global loads in flight across sync points.
// Block = (b, 64-row i-tile): 512 blocks x 512 threads, LDS ~32 KB.
// ---------------------------------------------------------------------------
__global__ __launch_bounds__(512, 4) void attn5_kernel(
    const float* __restrict__ adj, const unsigned short* __restrict__ hT,
    const float* __restrict__ s_in, const float* __restrict__ t_in,
    float* __restrict__ out)
{
    __shared__ unsigned short ht[128 * PSTR];     // 18 KB  [d][j]
    __shared__ unsigned short pt[64 * PSTR];      //  9 KB  [i][j]
    __shared__ float tl[N_];                      //  4 KB
    __shared__ float sl[64], rsl[64];

    const int tid = threadIdx.x;
    const int w   = tid >> 6;

    // XCD-chunked swizzle
    const int blk = (blockIdx.x & 7) * 64 + (blockIdx.x >> 3);
    const int b   = blk >> 4;
    const int i0  = (blk & 15) * 64;

    tl[tid]       = t_in[b * N_ + tid];
    tl[tid + 512] = t_in[b * N_ + tid + 512];
    if (tid < 64) sl[tid] = s_in[b * N_ + i0 + tid];

    // P-gen ids: 8 threads per i-row, 8 j each; adj loaded BY the consumer
    const int gi = tid >> 3;
    const int gj = (tid & 7) * 8;
    const float* arow = adj + ((size_t)(b * N_ + i0 + gi)) * N_ + gj;

    const unsigned short* hTb = hT + (size_t)b * F_ * N_;

    float4   a_reg[2][2];    // [k&1][half]  — static after full unroll
    short8_t h_reg[2][2];    // [k&1][chunk]
#define LOAD_A(K) do {                                                         \
    a_reg[(K) & 1][0] = *reinterpret_cast<const float4*>(arow + (K) * 64);     \
    a_reg[(K) & 1][1] = *reinterpret_cast<const float4*>(arow + (K) * 64 + 4); \
} while (0)
#define LOAD_H(K) do {                                                         \
    _Pragma("unroll")                                                          \
    for (int c = 0; c < 2; ++c) {                                              \
        int ch = tid + c * 512;                                                \
        h_reg[(K) & 1][c] = *reinterpret_cast<const short8_t*>(                \
            hTb + (size_t)(ch >> 3) * N_ + ((K) * 64 + (ch & 7) * 8));         \
    }                                                                          \
} while (0)

    // MFMA ids: 8 waves = 2m x 4n, per-wave 32x32
    const int m0 = (w >> 2) * 32;
    const int n0 = (w & 3) * 32;
    const int lm = tid & 15;
    const int kg = (tid & 63) >> 4;

    f32x4 acc[2][2];
    #pragma unroll
    for (int nf = 0; nf < 2; ++nf)
        #pragma unroll
        for (int mf = 0; mf < 2; ++mf) acc[nf][mf] = (f32x4){0.f, 0.f, 0.f, 0.f};
    float rs = 0.f;

    // prologue: tile-0 loads in flight; LDS (tl/sl) visible to all
    LOAD_A(0);
    LOAD_H(0);
    WAIT_LGKM();
    SCHEDB();
    BAR();
    const float s_i = sl[gi];

    #pragma unroll
    for (int k = 0; k < 16; ++k) {
        // a. issue k+1 loads into the OTHER reg buffers (fly over everything)
        if (k + 1 < 16) { LOAD_A(k + 1); LOAD_H(k + 1); }
        // b. stage ht from h_reg[k&1] (compiler waits precisely on these regs)
        #pragma unroll
        for (int c = 0; c < 2; ++c) {
            int ch = tid + c * 512;
            *reinterpret_cast<short8_t*>(&ht[(ch >> 3) * PSTR + (ch & 7) * 8]) =
                h_reg[k & 1][c];
        }
        // c. P-gen straight from a_reg[k&1]
        {
            float4 a0 = a_reg[k & 1][0];
            float4 a1 = a_reg[k & 1][1];
            float4 t0 = *reinterpret_cast<const float4*>(&tl[k * 64 + gj]);
            float4 t1 = *reinterpret_cast<const float4*>(&tl[k * 64 + gj + 4]);
            short4_t pk0, pk1;
            #pragma unroll
            for (int e = 0; e < 4; ++e) {
                float sc0 = s_i + (&t0.x)[e];
                sc0 = fmaxf(sc0, ALPHA_ * sc0);
                float p = __expf(sc0) * (&a0.x)[e];   // adj is exactly 0.0/1.0
                rs += p;
                pk0[e] = (short)bf16b(p);
            }
            #pragma unroll
            for (int e = 0; e < 4; ++e) {
                float sc1 = s_i + (&t1.x)[e];
                sc1 = fmaxf(sc1, ALPHA_ * sc1);
                float p = __expf(sc1) * (&a1.x)[e];
                rs += p;
                pk1[e] = (short)bf16b(p);
            }
            *reinterpret_cast<short4_t*>(&pt[gi * PSTR + gj])     = pk0;
            *reinterpret_cast<short4_t*>(&pt[gi * PSTR + gj + 4]) = pk1;
        }
        // d. ht/pt visible to all waves (lgkm only — global loads keep flying)
        WAIT_LGKM();
        SCHEDB();
        BAR();
        // e. MFMA
        #pragma unroll
        for (int ks = 0; ks < 2; ++ks) {
            short8_t b0 = *reinterpret_cast<const short8_t*>(
                &ht[(n0 + lm) * PSTR + ks * 32 + kg * 8]);
            short8_t b1 = *reinterpret_cast<const short8_t*>(
                &ht[(n0 + 16 + lm) * PSTR + ks * 32 + kg * 8]);
            short8_t a0f = *reinterpret_cast<const short8_t*>(
                &pt[(m0 + lm) * PSTR + ks * 32 + kg * 8]);
            short8_t a1f = *reinterpret_cast<const short8_t*>(
                &pt[(m0 + 16 + lm) * PSTR + ks * 32 + kg * 8]);
            acc[0][0] = __builtin_amdgcn_mfma_f32_16x16x32_bf16(a0f, b0, acc[0][0], 0, 0, 0);
            acc[1][0] = __builtin_amdgcn_mfma_f32_16x16x32_bf16(a0f, b1, acc[1][0], 0, 0, 0);
            acc[0][1] = __builtin_amdgcn_mfma_f32_16x16x32_bf16(a1f, b0, acc[0][1], 0, 0, 0);
            acc[1][1] = __builtin_amdgcn_mfma_f32_16x16x32_bf16(a1f, b1, acc[1][1], 0, 0, 0);
        }
        // f. protect ht/pt overwrite next iter (wave's own ds_reads already
        //    retired before MFMA issue; barrier orders across waves)
        BAR();
    }

    // rowsum over the 8 threads sharing gi
    rs += __shfl_xor(rs, 1);
    rs += __shfl_xor(rs, 2);
    rs += __shfl_xor(rs, 4);
    if ((tid & 7) == 0) rsl[gi] = 1.0f / rs;
    __syncthreads();

    const int rbase = m0 + ((tid & 63) >> 4) * 4;
    float* ob = out + ((size_t)(b * N_ + i0)) * F_;
    #pragma unroll
    for (int mf = 0; mf < 2; ++mf) {
        f32x4 inv = *reinterpret_cast<const f32x4*>(&rsl[rbase + mf * 16]);
        #pragma unroll
        for (int r = 0; r < 4; ++r) {
            int row = rbase + mf * 16 + r;
            #pragma unroll
            for (int nf = 0; nf < 2; ++nf)
                ob[(size_t)row * F_ + n0 + nf * 16 + lm] = acc[nf][mf][r] * inv[r];
        }
    }
#undef LOAD_A
#undef LOAD_H
}

// ---------------------------------------------------------------------------
extern "C" void kernel_launch(void* const* d_in, const int* in_sizes, int n_in,
                              void* d_out, int out_size, void* d_ws, size_t ws_size,
                              hipStream_t stream)
{
    const float* adj  = (const float*)d_in[0];   // (32,1024,1024)
    const float* feat = (const float*)d_in[1];   // (32,1024,128)
    const float* W    = (const float*)d_in[2];   // (128,128)
    const float* a    = (const float*)d_in[3];   // (256,1)
    float* out = (float*)d_out;                  // (32,1024,128) fp32

    unsigned short* hT = (unsigned short*)d_ws;                          // 8 MB
    float* s = (float*)((char*)d_ws + (size_t)B_ * F_ * N_ * 2);         // 128 KB
    float* t = s + (size_t)B_ * N_;                                      // 128 KB

    hst_kernel<<<(B_ * N_) / 64, 256, 0, stream>>>(feat, W, a, hT, s, t);
    attn5_kernel<<<B_ * 16, 512, 0, stream>>>(adj, hT, s, t, out);
}